// Round 3
// baseline (175.878 us; speedup 1.0000x reference)
//
#include <hip/hip_runtime.h>
#include <stdint.h>

#define B_ROWS 4096
#define D 256
#define NTOT (2 * B_ROWS)                    // 8192 rows
#define NSPLIT 16
#define BM 128                               // rows per gemm block
#define COLS_PER_BLOCK (NTOT / NSPLIT)       // 512
#define TILE_COLS 32
#define JT_COUNT (COLS_PER_BLOCK / TILE_COLS)  // 16
#define NBLOCKS ((NTOT / BM) * NSPLIT)       // 1024
#define C_SCALE 2.8853900817779268f          // (1/T)*log2(e) = 2*log2(e)

typedef __attribute__((ext_vector_type(8))) short bf16x8;
typedef __attribute__((ext_vector_type(4))) float f32x4;
typedef __attribute__((ext_vector_type(4))) unsigned short us4;

typedef const __attribute__((address_space(1))) char gch;
typedef __attribute__((address_space(3))) char lch;

static __device__ __forceinline__ unsigned short f2bf(float f) {
  union { float f; unsigned u; } v; v.f = f;
  unsigned r = v.u + 0x7FFFu + ((v.u >> 16) & 1u);   // RNE
  return (unsigned short)(r >> 16);
}

// ---- kernel 1: normalize rows -> bf16 zn, f32 pos; zero rowsum+counter ----
__global__ __launch_bounds__(256) void k_prep(const float* __restrict__ xi,
                                              const float* __restrict__ xj,
                                              unsigned short* __restrict__ zn,
                                              float* __restrict__ pos,
                                              float* __restrict__ rowsum,
                                              unsigned* __restrict__ counter) {
  if (blockIdx.x == 0 && threadIdx.x == 0) *counter = 0u;
  int p = blockIdx.x * 4 + (threadIdx.x >> 6);
  int lane = threadIdx.x & 63;
  float4 a = ((const float4*)(xi + (size_t)p * D))[lane];
  float4 b = ((const float4*)(xj + (size_t)p * D))[lane];
  float sa = a.x * a.x + a.y * a.y + a.z * a.z + a.w * a.w;
  float sb = b.x * b.x + b.y * b.y + b.z * b.z + b.w * b.w;
  float ab = a.x * b.x + a.y * b.y + a.z * b.z + a.w * b.w;
  #pragma unroll
  for (int m = 1; m < 64; m <<= 1) {
    sa += __shfl_xor(sa, m, 64);
    sb += __shfl_xor(sb, m, 64);
    ab += __shfl_xor(ab, m, 64);
  }
  float ia = 1.0f / fmaxf(sqrtf(sa), 1e-8f);
  float ib = 1.0f / fmaxf(sqrtf(sb), 1e-8f);
  us4 oa, ob;
  oa.x = f2bf(a.x * ia); oa.y = f2bf(a.y * ia);
  oa.z = f2bf(a.z * ia); oa.w = f2bf(a.w * ia);
  ob.x = f2bf(b.x * ib); ob.y = f2bf(b.y * ib);
  ob.z = f2bf(b.z * ib); ob.w = f2bf(b.w * ib);
  *(us4*)(zn + (size_t)p * D + lane * 4) = oa;
  *(us4*)(zn + (size_t)(p + B_ROWS) * D + lane * 4) = ob;
  if (lane == 0) {
    float d = ab * ia * ib;
    pos[p] = d;
    pos[p + B_ROWS] = d;
    rowsum[p] = 0.0f;
    rowsum[p + B_ROWS] = 0.0f;
  }
}

// ---- kernel 2: fused sim-GEMM + exp row-sum + last-block final loss ----
// r1-proven core: 256 threads (4 waves), BM=128, wave w owns rows
// [rb+32w, rb+32w+32) as two 16-row A-tiles held in registers. B staged in
// 32-col tiles (16 KB), double-buffered (32 KB LDS total = r1 footprint),
// stage(t+1) issued before compute(t), one vmcnt(0)+barrier per tile.
// global_load_lds: linear LDS dest + inverse-swizzled global src; reads
// apply the same XOR ((row&7)<<4) (rule #21).
__global__ __launch_bounds__(256) void k_gemm(const unsigned short* __restrict__ zn,
                                              const float* __restrict__ pos,
                                              float* __restrict__ rowsum,
                                              unsigned* __restrict__ counter,
                                              float* __restrict__ out) {
  __shared__ char lds[2 * TILE_COLS * 512];
  int rb = (int)(blockIdx.x / NSPLIT) * BM;
  int cb = (int)(blockIdx.x % NSPLIT) * COLS_PER_BLOCK;
  int w = threadIdx.x >> 6;
  int lane = threadIdx.x & 63;
  int hi = lane >> 4, lo = lane & 15;

  const char* znb = (const char*)zn;

  // A fragments (registers): lane -> row = lo, k = 32f + hi*8
  bf16x8 a0[8], a1[8];
  int r0 = rb + w * 32 + lo;
  #pragma unroll
  for (int f = 0; f < 8; f++) {
    a0[f] = *(const bf16x8*)(znb + (size_t)r0 * 512 + f * 64 + hi * 16);
    a1[f] = *(const bf16x8*)(znb + (size_t)(r0 + 16) * 512 + f * 64 + hi * 16);
  }

  // per-lane swizzled LDS read bases; nt*8192 / buf*16384 strides are
  // additive (XOR confined to bits 4..6)
  int rdbase[8];
  #pragma unroll
  for (int f = 0; f < 8; f++)
    rdbase[f] = lo * 512 + ((f * 64 + hi * 16) ^ ((lo & 7) << 4));

  float rs[2][4] = {{0.f, 0.f, 0.f, 0.f}, {0.f, 0.f, 0.f, 0.f}};

  auto stage = [&](int bufofs, int colrow) {
    #pragma unroll
    for (int it = 0; it < 4; it++) {
      int local = it * 4096 + w * 1024 + lane * 16;        // linear tile offset
      int src = local ^ (((local >> 9) & 7) << 4);         // inverse-swizzled src
      __builtin_amdgcn_global_load_lds(
          (gch*)(znb + (size_t)colrow * 512 + src),
          (lch*)(lds + bufofs + it * 4096 + w * 1024), 16, 0, 0);
    }
  };
  auto compute = [&](int bufofs) {
    #pragma unroll
    for (int nt = 0; nt < 2; nt++) {
      f32x4 acc0 = {0.f, 0.f, 0.f, 0.f}, acc1 = {0.f, 0.f, 0.f, 0.f};
      #pragma unroll
      for (int f = 0; f < 8; f++) {
        bf16x8 b = *(const bf16x8*)(lds + bufofs + nt * 8192 + rdbase[f]);
        acc0 = __builtin_amdgcn_mfma_f32_16x16x32_bf16(a0[f], b, acc0, 0, 0, 0);
        acc1 = __builtin_amdgcn_mfma_f32_16x16x32_bf16(a1[f], b, acc1, 0, 0, 0);
      }
      #pragma unroll
      for (int r = 0; r < 4; r++) {
        float e0, e1;
        asm("v_exp_f32 %0, %1" : "=v"(e0) : "v"(C_SCALE * acc0[r]));
        asm("v_exp_f32 %0, %1" : "=v"(e1) : "v"(C_SCALE * acc1[r]));
        rs[0][r] += e0;
        rs[1][r] += e1;
      }
    }
  };
  auto drain_barrier = []() {
    asm volatile("s_waitcnt vmcnt(0)" ::: "memory");
    __syncthreads();
  };

  stage(0, cb);                 // prologue
  drain_barrier();
  for (int jt = 0; jt < JT_COUNT; jt++) {
    if (jt + 1 < JT_COUNT) stage(((jt + 1) & 1) * 16384, cb + (jt + 1) * TILE_COLS);
    compute((jt & 1) * 16384);
    drain_barrier();
  }

  // reduce partial row-sums across the 16 lanes of each row-group
  #pragma unroll
  for (int m = 1; m < 16; m <<= 1) {
    #pragma unroll
    for (int t = 0; t < 2; t++)
      #pragma unroll
      for (int r = 0; r < 4; r++)
        rs[t][r] += __shfl_xor(rs[t][r], m, 64);
  }
  if (lo == 0) {
    #pragma unroll
    for (int t = 0; t < 2; t++)
      #pragma unroll
      for (int r = 0; r < 4; r++)
        atomicAdd(&rowsum[rb + w * 32 + t * 16 + hi * 4 + r], rs[t][r]);
  }

  // ---- last-block final reduction (saves one kernel node ~10 us) ----
  __threadfence();
  __shared__ unsigned s_done;
  if (threadIdx.x == 0) s_done = atomicAdd(counter, 1u);
  __syncthreads();
  if (s_done == NBLOCKS - 1) {
    float acc = 0.f;
    for (int i = threadIdx.x; i < NTOT; i += 256) {
      float s = __hip_atomic_load(&rowsum[i], __ATOMIC_RELAXED,
                                  __HIP_MEMORY_SCOPE_AGENT);
      acc += __logf(s - 7.3890560989306495f) - 2.0f * pos[i];
    }
    #pragma unroll
    for (int m = 1; m < 64; m <<= 1) acc += __shfl_xor(acc, m, 64);
    __shared__ float red[4];
    if (lane == 0) red[w] = acc;
    __syncthreads();
    if (threadIdx.x == 0)
      out[0] = (red[0] + red[1] + red[2] + red[3]) * (1.0f / NTOT);
  }
}

extern "C" void kernel_launch(void* const* d_in, const int* in_sizes, int n_in,
                              void* d_out, int out_size, void* d_ws, size_t ws_size,
                              hipStream_t stream) {
  const float* xi = (const float*)d_in[0];
  const float* xj = (const float*)d_in[1];

  unsigned short* zn = (unsigned short*)d_ws;                        // 4 MB
  char* base = (char*)(zn + (size_t)NTOT * D);
  float* rowsum = (float*)base;                                      // 32 KB
  float* pos = (float*)(base + (size_t)NTOT * 4);                    // 32 KB
  unsigned* counter = (unsigned*)(base + (size_t)2 * NTOT * 4);      // 4 B

  k_prep<<<B_ROWS / 4, 256, 0, stream>>>(xi, xj, zn, pos, rowsum, counter);
  k_gemm<<<NBLOCKS, 256, 0, stream>>>(zn, pos, rowsum, counter, (float*)d_out);
}

// Round 4
// 175.402 us; speedup vs baseline: 1.0027x; 1.0027x over previous
//
#include <hip/hip_runtime.h>
#include <stdint.h>

#define B_ROWS 4096
#define D 256
#define NTOT (2 * B_ROWS)                    // 8192 rows
#define NSPLIT 16
#define BM 128                               // rows per gemm block
#define COLS_PER_BLOCK (NTOT / NSPLIT)       // 512
#define TILE_COLS 32
#define JT_COUNT (COLS_PER_BLOCK / TILE_COLS)  // 16
#define NBLOCKS ((NTOT / BM) * NSPLIT)       // 1024
#define C_SCALE 2.8853900817779268f          // (1/T)*log2(e) = 2*log2(e)

typedef __attribute__((ext_vector_type(8))) short bf16x8;
typedef __attribute__((ext_vector_type(4))) float f32x4;
typedef __attribute__((ext_vector_type(4))) unsigned short us4;

typedef const __attribute__((address_space(1))) char gch;
typedef __attribute__((address_space(3))) char lch;

static __device__ __forceinline__ unsigned short f2bf(float f) {
  union { float f; unsigned u; } v; v.f = f;
  unsigned r = v.u + 0x7FFFu + ((v.u >> 16) & 1u);   // RNE
  return (unsigned short)(r >> 16);
}

// ---- kernel 1: normalize rows -> bf16 zn, f32 pos; zero rowsum+counter ----
__global__ __launch_bounds__(256) void k_prep(const float* __restrict__ xi,
                                              const float* __restrict__ xj,
                                              unsigned short* __restrict__ zn,
                                              float* __restrict__ pos,
                                              float* __restrict__ rowsum,
                                              unsigned* __restrict__ counter) {
  if (blockIdx.x == 0 && threadIdx.x == 0) *counter = 0u;
  int p = blockIdx.x * 4 + (threadIdx.x >> 6);
  int lane = threadIdx.x & 63;
  float4 a = ((const float4*)(xi + (size_t)p * D))[lane];
  float4 b = ((const float4*)(xj + (size_t)p * D))[lane];
  float sa = a.x * a.x + a.y * a.y + a.z * a.z + a.w * a.w;
  float sb = b.x * b.x + b.y * b.y + b.z * b.z + b.w * b.w;
  float ab = a.x * b.x + a.y * b.y + a.z * b.z + a.w * b.w;
  #pragma unroll
  for (int m = 1; m < 64; m <<= 1) {
    sa += __shfl_xor(sa, m, 64);
    sb += __shfl_xor(sb, m, 64);
    ab += __shfl_xor(ab, m, 64);
  }
  float ia = 1.0f / fmaxf(sqrtf(sa), 1e-8f);
  float ib = 1.0f / fmaxf(sqrtf(sb), 1e-8f);
  us4 oa, ob;
  oa.x = f2bf(a.x * ia); oa.y = f2bf(a.y * ia);
  oa.z = f2bf(a.z * ia); oa.w = f2bf(a.w * ia);
  ob.x = f2bf(b.x * ib); ob.y = f2bf(b.y * ib);
  ob.z = f2bf(b.z * ib); ob.w = f2bf(b.w * ib);
  *(us4*)(zn + (size_t)p * D + lane * 4) = oa;
  *(us4*)(zn + (size_t)(p + B_ROWS) * D + lane * 4) = ob;
  if (lane == 0) {
    float d = ab * ia * ib;
    pos[p] = d;
    pos[p + B_ROWS] = d;
    rowsum[p] = 0.0f;
    rowsum[p + B_ROWS] = 0.0f;
  }
}

// ---- kernel 2: fused sim-GEMM + exp row-sum + last-block final loss ----
// r1-proven core (NO lambdas — r2/r3's capturing lambdas forced the A
// fragments to scratch: VGPR 112->68, MfmaUtil 28->11%). 256 threads
// (4 waves), BM=128; wave w owns rows [rb+32w, rb+32w+32) as two 16-row
// A-tiles in registers. B staged in 32-col tiles (16 KB), double-buffered
// (32 KB LDS = r1 footprint): stage(t+1) issued, compute(t), then one
// vmcnt(0)+barrier per tile (T3 minimum 2-phase recipe).
// global_load_lds: linear LDS dest + inverse-swizzled global src; reads
// apply the same XOR ((row&7)<<4) (rule #21).
__global__ __launch_bounds__(256) void k_gemm(const unsigned short* __restrict__ zn,
                                              const float* __restrict__ pos,
                                              float* __restrict__ rowsum,
                                              unsigned* __restrict__ counter,
                                              float* __restrict__ out) {
  __shared__ char lds[2 * TILE_COLS * 512];
  int rb = (int)(blockIdx.x / NSPLIT) * BM;
  int cb = (int)(blockIdx.x % NSPLIT) * COLS_PER_BLOCK;
  int w = threadIdx.x >> 6;
  int lane = threadIdx.x & 63;
  int hi = lane >> 4, lo = lane & 15;

  const char* znb = (const char*)zn;
  const char* colp = znb + (size_t)cb * 512;

  // A fragments (registers): lane -> row = lo, k = 32f + hi*8
  bf16x8 a0[8], a1[8];
  int r0 = rb + w * 32 + lo;
  #pragma unroll
  for (int f = 0; f < 8; f++) {
    a0[f] = *(const bf16x8*)(znb + (size_t)r0 * 512 + f * 64 + hi * 16);
    a1[f] = *(const bf16x8*)(znb + (size_t)(r0 + 16) * 512 + f * 64 + hi * 16);
  }

  // per-lane swizzled LDS read bases; nt*8192 / buf*16384 strides are
  // additive (XOR confined to bits 4..6)
  int rdbase[8];
  #pragma unroll
  for (int f = 0; f < 8; f++)
    rdbase[f] = lo * 512 + ((f * 64 + hi * 16) ^ ((lo & 7) << 4));

  // per-lane staging offsets (linear LDS dest; inverse-swizzled global src)
  int st_local[4], st_src[4];
  #pragma unroll
  for (int it = 0; it < 4; it++) {
    st_local[it] = it * 4096 + w * 1024 + lane * 16;
    st_src[it] = st_local[it] ^ (((st_local[it] >> 9) & 7) << 4);
  }

  float rs[2][4] = {{0.f, 0.f, 0.f, 0.f}, {0.f, 0.f, 0.f, 0.f}};

  // prologue: stage tile 0 into buffer 0
  #pragma unroll
  for (int it = 0; it < 4; it++)
    __builtin_amdgcn_global_load_lds((gch*)(colp + st_src[it]),
                                     (lch*)(lds + st_local[it]), 16, 0, 0);
  asm volatile("s_waitcnt vmcnt(0)" ::: "memory");
  __syncthreads();

  for (int jt = 0; jt < JT_COUNT; jt++) {
    // issue next tile's stage into the other buffer
    if (jt + 1 < JT_COUNT) {
      int nbuf = ((jt + 1) & 1) * 16384;
      const char* src = colp + (size_t)(jt + 1) * TILE_COLS * 512;
      #pragma unroll
      for (int it = 0; it < 4; it++)
        __builtin_amdgcn_global_load_lds((gch*)(src + st_src[it]),
                                         (lch*)(lds + nbuf + st_local[it]),
                                         16, 0, 0);
    }
    // compute current tile
    int cbuf = (jt & 1) * 16384;
    #pragma unroll
    for (int nt = 0; nt < 2; nt++) {
      f32x4 acc0 = {0.f, 0.f, 0.f, 0.f}, acc1 = {0.f, 0.f, 0.f, 0.f};
      #pragma unroll
      for (int f = 0; f < 8; f++) {
        bf16x8 b = *(const bf16x8*)(lds + cbuf + nt * 8192 + rdbase[f]);
        acc0 = __builtin_amdgcn_mfma_f32_16x16x32_bf16(a0[f], b, acc0, 0, 0, 0);
        acc1 = __builtin_amdgcn_mfma_f32_16x16x32_bf16(a1[f], b, acc1, 0, 0, 0);
      }
      #pragma unroll
      for (int r = 0; r < 4; r++) {
        float t0 = C_SCALE * acc0[r];
        float t1 = C_SCALE * acc1[r];
        float e0, e1;
        asm("v_exp_f32 %0, %1" : "=v"(e0) : "v"(t0));
        asm("v_exp_f32 %0, %1" : "=v"(e1) : "v"(t1));
        rs[0][r] += e0;
        rs[1][r] += e1;
      }
    }
    asm volatile("s_waitcnt vmcnt(0)" ::: "memory");
    __syncthreads();
  }

  // reduce partial row-sums across the 16 lanes of each row-group
  #pragma unroll
  for (int m = 1; m < 16; m <<= 1) {
    #pragma unroll
    for (int t = 0; t < 2; t++)
      #pragma unroll
      for (int r = 0; r < 4; r++)
        rs[t][r] += __shfl_xor(rs[t][r], m, 64);
  }
  if (lo == 0) {
    #pragma unroll
    for (int t = 0; t < 2; t++)
      #pragma unroll
      for (int r = 0; r < 4; r++)
        atomicAdd(&rowsum[rb + w * 32 + t * 16 + hi * 4 + r], rs[t][r]);
  }

  // ---- last-block final reduction (saves one kernel node) ----
  __threadfence();
  __shared__ unsigned s_done;
  if (threadIdx.x == 0) s_done = atomicAdd(counter, 1u);
  __syncthreads();
  if (s_done == NBLOCKS - 1) {
    float acc = 0.f;
    for (int i = threadIdx.x; i < NTOT; i += 256) {
      float s = __hip_atomic_load(&rowsum[i], __ATOMIC_RELAXED,
                                  __HIP_MEMORY_SCOPE_AGENT);
      acc += __logf(s - 7.3890560989306495f) - 2.0f * pos[i];
    }
    #pragma unroll
    for (int m = 1; m < 64; m <<= 1) acc += __shfl_xor(acc, m, 64);
    __shared__ float red[4];
    if (lane == 0) red[w] = acc;
    __syncthreads();
    if (threadIdx.x == 0)
      out[0] = (red[0] + red[1] + red[2] + red[3]) * (1.0f / NTOT);
  }
}

extern "C" void kernel_launch(void* const* d_in, const int* in_sizes, int n_in,
                              void* d_out, int out_size, void* d_ws, size_t ws_size,
                              hipStream_t stream) {
  const float* xi = (const float*)d_in[0];
  const float* xj = (const float*)d_in[1];

  unsigned short* zn = (unsigned short*)d_ws;                        // 4 MB
  char* base = (char*)(zn + (size_t)NTOT * D);
  float* rowsum = (float*)base;                                      // 32 KB
  float* pos = (float*)(base + (size_t)NTOT * 4);                    // 32 KB
  unsigned* counter = (unsigned*)(base + (size_t)2 * NTOT * 4);      // 4 B

  k_prep<<<B_ROWS / 4, 256, 0, stream>>>(xi, xj, zn, pos, rowsum, counter);
  k_gemm<<<NBLOCKS, 256, 0, stream>>>(zn, pos, rowsum, counter, (float*)d_out);
}

// Round 5
// 156.625 us; speedup vs baseline: 1.1229x; 1.1199x over previous
//
#include <hip/hip_runtime.h>
#include <stdint.h>

#define B_ROWS 4096
#define D 256
#define NTOT (2 * B_ROWS)                    // 8192 rows
#define NSPLIT 16
#define BM 128                               // rows per gemm block
#define COLS_PER_BLOCK (NTOT / NSPLIT)       // 512
#define TILE_COLS 32
#define JT_COUNT (COLS_PER_BLOCK / TILE_COLS)  // 16
#define NBLOCKS ((NTOT / BM) * NSPLIT)       // 1024
#define C_SCALE 2.8853900817779268f          // (1/T)*log2(e) = 2*log2(e)

typedef __attribute__((ext_vector_type(8))) short bf16x8;
typedef __attribute__((ext_vector_type(4))) float f32x4;
typedef __attribute__((ext_vector_type(4))) unsigned short us4;

typedef const __attribute__((address_space(1))) char gch;
typedef __attribute__((address_space(3))) char lch;

static __device__ __forceinline__ unsigned short f2bf(float f) {
  union { float f; unsigned u; } v; v.f = f;
  unsigned r = v.u + 0x7FFFu + ((v.u >> 16) & 1u);   // RNE
  return (unsigned short)(r >> 16);
}

// ---- kernel 1: normalize rows -> bf16 zn, f32 pos; zero rowsum+counter ----
__global__ __launch_bounds__(256) void k_prep(const float* __restrict__ xi,
                                              const float* __restrict__ xj,
                                              unsigned short* __restrict__ zn,
                                              float* __restrict__ pos,
                                              float* __restrict__ rowsum,
                                              unsigned* __restrict__ counter) {
  if (blockIdx.x == 0 && threadIdx.x == 0) *counter = 0u;
  int p = blockIdx.x * 4 + (threadIdx.x >> 6);
  int lane = threadIdx.x & 63;
  float4 a = ((const float4*)(xi + (size_t)p * D))[lane];
  float4 b = ((const float4*)(xj + (size_t)p * D))[lane];
  float sa = a.x * a.x + a.y * a.y + a.z * a.z + a.w * a.w;
  float sb = b.x * b.x + b.y * b.y + b.z * b.z + b.w * b.w;
  float ab = a.x * b.x + a.y * b.y + a.z * b.z + a.w * b.w;
  #pragma unroll
  for (int m = 1; m < 64; m <<= 1) {
    sa += __shfl_xor(sa, m, 64);
    sb += __shfl_xor(sb, m, 64);
    ab += __shfl_xor(ab, m, 64);
  }
  float ia = 1.0f / fmaxf(sqrtf(sa), 1e-8f);
  float ib = 1.0f / fmaxf(sqrtf(sb), 1e-8f);
  us4 oa, ob;
  oa.x = f2bf(a.x * ia); oa.y = f2bf(a.y * ia);
  oa.z = f2bf(a.z * ia); oa.w = f2bf(a.w * ia);
  ob.x = f2bf(b.x * ib); ob.y = f2bf(b.y * ib);
  ob.z = f2bf(b.z * ib); ob.w = f2bf(b.w * ib);
  *(us4*)(zn + (size_t)p * D + lane * 4) = oa;
  *(us4*)(zn + (size_t)(p + B_ROWS) * D + lane * 4) = ob;
  if (lane == 0) {
    float d = ab * ia * ib;
    pos[p] = d;
    pos[p + B_ROWS] = d;
    rowsum[p] = 0.0f;
    rowsum[p + B_ROWS] = 0.0f;
  }
}

// ---- kernel 2: fused sim-GEMM + exp row-sum + last-block final loss ----
// Identical to r4 EXCEPT __launch_bounds__(256, 4): r3/r4's VGPR_Count=68
// is the 8-waves/SIMD tier (512/8=64) — the backend's occupancy heuristic
// spilled the 64 VGPRs of A-fragments to scratch to reach it (MfmaUtil
// 28%->11%). Pinning 4 waves/EU sets the budget to 128 VGPR, which fits
// the kernel's natural ~112, and gives 4 blocks/CU (LDS 33KB*4 <= 160KB).
__global__ __launch_bounds__(256, 4) void k_gemm(const unsigned short* __restrict__ zn,
                                                 const float* __restrict__ pos,
                                                 float* __restrict__ rowsum,
                                                 unsigned* __restrict__ counter,
                                                 float* __restrict__ out) {
  __shared__ char lds[2 * TILE_COLS * 512];
  int rb = (int)(blockIdx.x / NSPLIT) * BM;
  int cb = (int)(blockIdx.x % NSPLIT) * COLS_PER_BLOCK;
  int w = threadIdx.x >> 6;
  int lane = threadIdx.x & 63;
  int hi = lane >> 4, lo = lane & 15;

  const char* znb = (const char*)zn;
  const char* colp = znb + (size_t)cb * 512;

  // A fragments (registers): lane -> row = lo, k = 32f + hi*8
  bf16x8 a0[8], a1[8];
  int r0 = rb + w * 32 + lo;
  #pragma unroll
  for (int f = 0; f < 8; f++) {
    a0[f] = *(const bf16x8*)(znb + (size_t)r0 * 512 + f * 64 + hi * 16);
    a1[f] = *(const bf16x8*)(znb + (size_t)(r0 + 16) * 512 + f * 64 + hi * 16);
  }

  // per-lane swizzled LDS read bases; nt*8192 / buf*16384 strides are
  // additive (XOR confined to bits 4..6)
  int rdbase[8];
  #pragma unroll
  for (int f = 0; f < 8; f++)
    rdbase[f] = lo * 512 + ((f * 64 + hi * 16) ^ ((lo & 7) << 4));

  // per-lane staging offsets (linear LDS dest; inverse-swizzled global src)
  int st_local[4], st_src[4];
  #pragma unroll
  for (int it = 0; it < 4; it++) {
    st_local[it] = it * 4096 + w * 1024 + lane * 16;
    st_src[it] = st_local[it] ^ (((st_local[it] >> 9) & 7) << 4);
  }

  float rs[2][4] = {{0.f, 0.f, 0.f, 0.f}, {0.f, 0.f, 0.f, 0.f}};

  // prologue: stage tile 0 into buffer 0
  #pragma unroll
  for (int it = 0; it < 4; it++)
    __builtin_amdgcn_global_load_lds((gch*)(colp + st_src[it]),
                                     (lch*)(lds + st_local[it]), 16, 0, 0);
  asm volatile("s_waitcnt vmcnt(0)" ::: "memory");
  __syncthreads();

  for (int jt = 0; jt < JT_COUNT; jt++) {
    // issue next tile's stage into the other buffer
    if (jt + 1 < JT_COUNT) {
      int nbuf = ((jt + 1) & 1) * 16384;
      const char* src = colp + (size_t)(jt + 1) * TILE_COLS * 512;
      #pragma unroll
      for (int it = 0; it < 4; it++)
        __builtin_amdgcn_global_load_lds((gch*)(src + st_src[it]),
                                         (lch*)(lds + nbuf + st_local[it]),
                                         16, 0, 0);
    }
    // compute current tile
    int cbuf = (jt & 1) * 16384;
    #pragma unroll
    for (int nt = 0; nt < 2; nt++) {
      f32x4 acc0 = {0.f, 0.f, 0.f, 0.f}, acc1 = {0.f, 0.f, 0.f, 0.f};
      #pragma unroll
      for (int f = 0; f < 8; f++) {
        bf16x8 b = *(const bf16x8*)(lds + cbuf + nt * 8192 + rdbase[f]);
        acc0 = __builtin_amdgcn_mfma_f32_16x16x32_bf16(a0[f], b, acc0, 0, 0, 0);
        acc1 = __builtin_amdgcn_mfma_f32_16x16x32_bf16(a1[f], b, acc1, 0, 0, 0);
      }
      #pragma unroll
      for (int r = 0; r < 4; r++) {
        float t0 = C_SCALE * acc0[r];
        float t1 = C_SCALE * acc1[r];
        float e0, e1;
        asm("v_exp_f32 %0, %1" : "=v"(e0) : "v"(t0));
        asm("v_exp_f32 %0, %1" : "=v"(e1) : "v"(t1));
        rs[0][r] += e0;
        rs[1][r] += e1;
      }
    }
    asm volatile("s_waitcnt vmcnt(0)" ::: "memory");
    __syncthreads();
  }

  // reduce partial row-sums across the 16 lanes of each row-group
  #pragma unroll
  for (int m = 1; m < 16; m <<= 1) {
    #pragma unroll
    for (int t = 0; t < 2; t++)
      #pragma unroll
      for (int r = 0; r < 4; r++)
        rs[t][r] += __shfl_xor(rs[t][r], m, 64);
  }
  if (lo == 0) {
    #pragma unroll
    for (int t = 0; t < 2; t++)
      #pragma unroll
      for (int r = 0; r < 4; r++)
        atomicAdd(&rowsum[rb + w * 32 + t * 16 + hi * 4 + r], rs[t][r]);
  }

  // ---- last-block final reduction (saves one kernel node) ----
  __threadfence();
  __shared__ unsigned s_done;
  if (threadIdx.x == 0) s_done = atomicAdd(counter, 1u);
  __syncthreads();
  if (s_done == NBLOCKS - 1) {
    float acc = 0.f;
    for (int i = threadIdx.x; i < NTOT; i += 256) {
      float s = __hip_atomic_load(&rowsum[i], __ATOMIC_RELAXED,
                                  __HIP_MEMORY_SCOPE_AGENT);
      acc += __logf(s - 7.3890560989306495f) - 2.0f * pos[i];
    }
    #pragma unroll
    for (int m = 1; m < 64; m <<= 1) acc += __shfl_xor(acc, m, 64);
    __shared__ float red[4];
    if (lane == 0) red[w] = acc;
    __syncthreads();
    if (threadIdx.x == 0)
      out[0] = (red[0] + red[1] + red[2] + red[3]) * (1.0f / NTOT);
  }
}

extern "C" void kernel_launch(void* const* d_in, const int* in_sizes, int n_in,
                              void* d_out, int out_size, void* d_ws, size_t ws_size,
                              hipStream_t stream) {
  const float* xi = (const float*)d_in[0];
  const float* xj = (const float*)d_in[1];

  unsigned short* zn = (unsigned short*)d_ws;                        // 4 MB
  char* base = (char*)(zn + (size_t)NTOT * D);
  float* rowsum = (float*)base;                                      // 32 KB
  float* pos = (float*)(base + (size_t)NTOT * 4);                    // 32 KB
  unsigned* counter = (unsigned*)(base + (size_t)2 * NTOT * 4);      // 4 B

  k_prep<<<B_ROWS / 4, 256, 0, stream>>>(xi, xj, zn, pos, rowsum, counter);
  k_gemm<<<NBLOCKS, 256, 0, stream>>>(zn, pos, rowsum, counter, (float*)d_out);
}